// Round 10
// baseline (276.350 us; speedup 1.0000x reference)
//
#include <hip/hip_runtime.h>
#include <hip/hip_fp16.h>

// GraphSAGE 2-layer encoder — R10: single-pass partition via parallel bases.
// R9 postmortem: partition branch was ~60us of the 63us fused kernel — three
// LDS-atomic passes per edge chunk on only 196 blocks (latency-bound, occ 8%).
// R10: hist -> Hmat[blk][bucket] (coalesced), bucket-total scan, then a
// wave-per-bucket shuffle-scan turns Hmat into absolute per-(block,bucket)
// write bases (R7's bases idea WITHOUT the serial global RMW chain). The
// fused partition is then one pass: load cursor row, scatter. MFMA gemm and
// in-LDS-sort gather unchanged (measured at/near floor).

#define DIM 64
#define BN 64                 // nodes per bucket (dst >> 6)
#define MAXBUCK 2048          // LDS bound (nbuck = 1563)
#define CHUNK 4096            // edges per hist/partition block (391 blocks)
#define GCAP 2048             // LDS edge capacity per gather block
#define WT_STRIDE 72          // padded k-stride of W^T in LDS (halves)

using f16x8 = __attribute__((ext_vector_type(8))) _Float16;
using f32x4 = __attribute__((ext_vector_type(4))) float;

// accumulate 8 halves (float4 bit-pattern) into acc[8]
__device__ inline void addh8(float* acc, float4 raw) {
    const __half2* hp = (const __half2*)&raw;
#pragma unroll
    for (int k = 0; k < 4; ++k) {
        float2 f = __half22float2(hp[k]);
        acc[2 * k]     += f.x;
        acc[2 * k + 1] += f.y;
    }
}

// ---- histogram: per-chunk counts -> Hmat[blk][bucket] + global totals ----
__global__ __launch_bounds__(256) void hist_kernel(const int* __restrict__ dst,
                                                   int* __restrict__ Hmat,
                                                   int* __restrict__ ghist,
                                                   int nE, int nbuck) {
    __shared__ int hist[MAXBUCK];
    const int t = threadIdx.x;
    for (int k = t; k < nbuck; k += 256) hist[k] = 0;
    __syncthreads();
    const int base = blockIdx.x * CHUNK;
    const int end = min(nE, base + CHUNK);
    for (int i = base + t; i < end; i += 256)
        atomicAdd(&hist[dst[i] >> 6], 1);
    __syncthreads();
    int* row = Hmat + (size_t)blockIdx.x * nbuck;
    for (int k = t; k < nbuck; k += 256) {
        int h = hist[k];
        row[k] = h;                       // coalesced
        if (h) atomicAdd(&ghist[k], h);
    }
}

// ---- exclusive scan of bucket totals (1 block, up to 2048) -> boff ----
__global__ __launch_bounds__(1024) void scan_kernel(const int* __restrict__ ghist,
                                                    int* __restrict__ boff, int nbuck) {
    __shared__ int sa[2048], sb[2048];
    const int t = threadIdx.x;
    int v0 = (t < nbuck) ? ghist[t] : 0;
    int v1 = (t + 1024 < nbuck) ? ghist[t + 1024] : 0;
    sa[t] = v0; sa[t + 1024] = v1;
    __syncthreads();
    int* in = sa; int* out = sb;
    for (int d = 1; d < 2048; d <<= 1) {
        out[t] = in[t] + ((t >= d) ? in[t - d] : 0);
        int i2 = t + 1024;
        out[i2] = in[i2] + ((i2 >= d) ? in[i2 - d] : 0);
        __syncthreads();
        int* tmp = in; in = out; out = tmp;
    }
    if (t < nbuck) boff[t] = in[t] - v0;
    if (t + 1024 < nbuck) boff[t + 1024] = in[t + 1024] - v1;
    if (t == 0) boff[nbuck] = in[2047];
}

// ---- bases: one WAVE per bucket scans Hmat[:,k] over the block axis,
// rewriting counts into absolute write bases (boff[k] + exclusive prefix).
__global__ __launch_bounds__(256) void bases_kernel(int* __restrict__ Hmat,
                                                    const int* __restrict__ boff,
                                                    int nbuck, int nblk) {
    const int k = blockIdx.x * 4 + (threadIdx.x >> 6);
    if (k >= nbuck) return;
    const int lane = threadIdx.x & 63;
    int run = boff[k];
    for (int j0 = 0; j0 < nblk; j0 += 64) {
        int j = j0 + lane;
        int v = (j < nblk) ? Hmat[(size_t)j * nbuck + k] : 0;
        int s = v;
#pragma unroll
        for (int d = 1; d < 64; d <<= 1) {
            int u = __shfl_up(s, d);
            if (lane >= d) s += u;
        }
        if (j < nblk) Hmat[(size_t)j * nbuck + k] = run + (s - v);
        run += __shfl(s, 63);   // chunk total
    }
}

// ---- B-fragment loaders: lane's node row, k = ki*32 + quad*8 + j ----
__device__ inline void load_bfrag(const __half* __restrict__ H, long long nn, int lq,
                                  f16x8& b0, f16x8& b1) {
    b0 = *(const f16x8*)&H[nn * 64 + lq * 8];
    b1 = *(const f16x8*)&H[nn * 64 + 32 + lq * 8];
}
__device__ inline void load_bfrag(const float* __restrict__ H, long long nn, int lq,
                                  f16x8& b0, f16x8& b1) {
    const float* p = &H[nn * 64 + lq * 8];
    float4 u0 = *(const float4*)p;
    float4 u1 = *(const float4*)(p + 4);
    float4 u2 = *(const float4*)(p + 32);
    float4 u3 = *(const float4*)(p + 36);
    b0[0] = (_Float16)u0.x; b0[1] = (_Float16)u0.y; b0[2] = (_Float16)u0.z; b0[3] = (_Float16)u0.w;
    b0[4] = (_Float16)u1.x; b0[5] = (_Float16)u1.y; b0[6] = (_Float16)u1.z; b0[7] = (_Float16)u1.w;
    b1[0] = (_Float16)u2.x; b1[1] = (_Float16)u2.y; b1[2] = (_Float16)u2.z; b1[3] = (_Float16)u2.w;
    b1[4] = (_Float16)u3.x; b1[5] = (_Float16)u3.y; b1[6] = (_Float16)u3.z; b1[7] = (_Float16)u3.w;
}

// ---- MFMA dual-GEMM body: A(fp16)=H@Wl ; D(fp16)=H@Wr+bias; 256 nodes/block.
template <typename InT>
__device__ void gemm_body(int bid, __half* wt,
                          const InT* __restrict__ H,
                          const float* __restrict__ Wl, const float* __restrict__ Wr,
                          const float* __restrict__ bias,
                          __half* __restrict__ A, __half* __restrict__ Dbuf, int n) {
    const int t = threadIdx.x;
    for (int i = t; i < 4096; i += 256) {
        int k = i >> 6, m = i & 63;
        wt[(size_t)m * WT_STRIDE + k] = __float2half(Wl[i]);
        wt[(size_t)(64 + m) * WT_STRIDE + k] = __float2half(Wr[i]);
    }
    __syncthreads();
    const int lane = t & 63, wave = t >> 6;
    const int ln = lane & 15, lq = lane >> 4;
    f16x8 af[2][4][2];
#pragma unroll
    for (int mat = 0; mat < 2; ++mat)
#pragma unroll
        for (int mt = 0; mt < 4; ++mt)
#pragma unroll
            for (int ki = 0; ki < 2; ++ki)
                af[mat][mt][ki] = *(const f16x8*)&wt[(size_t)(mat * 64 + mt * 16 + ln) * WT_STRIDE
                                                     + ki * 32 + lq * 8];
    float4 bf[4];
#pragma unroll
    for (int mt = 0; mt < 4; ++mt)
        bf[mt] = *(const float4*)&bias[mt * 16 + lq * 4];

    const int base = bid * 256;
    for (int it = 0; it < 4; ++it) {
        const int node = base + it * 64 + wave * 16 + ln;
        const long long nn = (node < n) ? node : (n - 1);
        f16x8 b0, b1;
        load_bfrag(H, nn, lq, b0, b1);
        f32x4 acc[2][4];
#pragma unroll
        for (int mat = 0; mat < 2; ++mat)
#pragma unroll
            for (int mt = 0; mt < 4; ++mt) {
                f32x4 z = {0.f, 0.f, 0.f, 0.f};
                z = __builtin_amdgcn_mfma_f32_16x16x32_f16(af[mat][mt][0], b0, z, 0, 0, 0);
                z = __builtin_amdgcn_mfma_f32_16x16x32_f16(af[mat][mt][1], b1, z, 0, 0, 0);
                acc[mat][mt] = z;
            }
        if (node < n) {
#pragma unroll
            for (int mt = 0; mt < 4; ++mt) {
                union { __half2 h[2]; float2 f; } u;
                u.h[0] = __floats2half2_rn(acc[0][mt][0], acc[0][mt][1]);
                u.h[1] = __floats2half2_rn(acc[0][mt][2], acc[0][mt][3]);
                *(float2*)&A[(size_t)node * 64 + mt * 16 + lq * 4] = u.f;
                union { __half2 h[2]; float2 f; } v;
                v.h[0] = __floats2half2_rn(acc[1][mt][0] + bf[mt].x, acc[1][mt][1] + bf[mt].y);
                v.h[1] = __floats2half2_rn(acc[1][mt][2] + bf[mt].z, acc[1][mt][3] + bf[mt].w);
                *(float2*)&Dbuf[(size_t)node * 64 + mt * 16 + lq * 4] = v.f;
            }
        }
    }
}

// ---- fused dispatch: blocks [0,pb) single-pass partition, [pb,..) gemm ----
__global__ __launch_bounds__(256) void part_gemm_kernel(const int* __restrict__ src,
                                                        const int* __restrict__ dst,
                                                        const int* __restrict__ Hmat,
                                                        unsigned* __restrict__ P,
                                                        int nE, int nbuck, int pb,
                                                        const float* __restrict__ H,
                                                        const float* __restrict__ Wl,
                                                        const float* __restrict__ Wr,
                                                        const float* __restrict__ bias,
                                                        __half* __restrict__ A,
                                                        __half* __restrict__ Dbuf, int n) {
    __shared__ __align__(16) unsigned short smem_u[2 * 64 * WT_STRIDE];  // 18KB >= 8KB cur
    if ((int)blockIdx.x < pb) {
        int* cur = (int*)smem_u;
        const int t = threadIdx.x;
        const int* row = Hmat + (size_t)blockIdx.x * nbuck;
        for (int k = t; k < nbuck; k += 256) cur[k] = row[k];   // coalesced bases
        __syncthreads();
        const int base = blockIdx.x * CHUNK;
        const int end = min(nE, base + CHUNK);
        for (int i = base + t; i < end; i += 256) {
            int d = dst[i];
            int bk = d >> 6;
            int pos = atomicAdd(&cur[bk], 1);
            P[pos] = ((unsigned)src[i] << 6) | (unsigned)(d & 63);
        }
    } else {
        gemm_body(blockIdx.x - pb, (__half*)smem_u, H, Wl, Wr, bias, A, Dbuf, n);
    }
}

// ---- standalone gemm (layer 2, fp16 input) ----
__global__ __launch_bounds__(256) void gemm_kernel(const __half* __restrict__ H,
                                                   const float* __restrict__ Wl,
                                                   const float* __restrict__ Wr,
                                                   const float* __restrict__ bias,
                                                   __half* __restrict__ A,
                                                   __half* __restrict__ Dbuf, int n) {
    __shared__ __align__(16) unsigned short smem_u[2 * 64 * WT_STRIDE];
    gemm_body(blockIdx.x, (__half*)smem_u, H, Wl, Wr, bias, A, Dbuf, n);
}

// ---- gather with fused in-LDS bucket sort; out = act(mean + D) ----
template <bool RELU, typename OutT>
__global__ __launch_bounds__(256) void gather_sort_combine(const __half* __restrict__ A,
                                                           const __half* __restrict__ Dbuf,
                                                           const int* __restrict__ boff,
                                                           const unsigned* __restrict__ P,
                                                           int* __restrict__ spill,
                                                           OutT* __restrict__ out, int n) {
    __shared__ int hist[BN];
    __shared__ int rstart[BN];
    __shared__ int cur[BN];
    __shared__ int lsrc[GCAP];
    const int t = threadIdx.x;
    const int b = blockIdx.x;
    if (t < BN) hist[t] = 0;
    __syncthreads();
    const int start = boff[b], end = boff[b + 1];
    const int m = end - start;
    for (int i = start + t; i < end; i += 256)
        atomicAdd(&hist[P[i] & 63], 1);
    __syncthreads();
    if (t < 64) {
        int v = hist[t];
        int s = v;
#pragma unroll
        for (int d = 1; d < 64; d <<= 1) {
            int u = __shfl_up(s, d);
            if (t >= d) s += u;
        }
        rstart[t] = s - v;
        cur[t] = s - v;
    }
    __syncthreads();
    int* list = (m <= GCAP) ? (int*)lsrc : (spill + start);
    for (int i = start + t; i < end; i += 256) {
        unsigned p = P[i];
        int pos = atomicAdd(&cur[p & 63], 1);
        list[pos] = (int)(p >> 6);
    }
    __syncthreads();
    const int dg = t & 7;
    const size_t doff = (size_t)dg * 8;
    for (int pass = 0; pass < 2; ++pass) {
        const int r = pass * 32 + (t >> 3);
        const int node = b * BN + r;
        if (node >= n) continue;
        const int c = hist[r];
        const int* sp = list + rstart[r];
        float acc[8] = {0.f, 0.f, 0.f, 0.f, 0.f, 0.f, 0.f, 0.f};
        int j = 0;
        for (; j + 4 <= c; j += 4) {
            int e0 = sp[j + 0], e1 = sp[j + 1], e2 = sp[j + 2], e3 = sp[j + 3];
            float4 r0 = *(const float4*)&A[(size_t)e0 * 64 + doff];
            float4 r1 = *(const float4*)&A[(size_t)e1 * 64 + doff];
            float4 r2 = *(const float4*)&A[(size_t)e2 * 64 + doff];
            float4 r3 = *(const float4*)&A[(size_t)e3 * 64 + doff];
            addh8(acc, r0); addh8(acc, r1); addh8(acc, r2); addh8(acc, r3);
        }
        for (; j < c; ++j) {
            float4 rr = *(const float4*)&A[(size_t)sp[j] * 64 + doff];
            addh8(acc, rr);
        }
        const float inv = 1.0f / fmaxf((float)c, 1.0f);
        float d8[8] = {0, 0, 0, 0, 0, 0, 0, 0};
        addh8(d8, *(const float4*)&Dbuf[(size_t)node * 64 + doff]);
        float o[8];
#pragma unroll
        for (int k = 0; k < 8; ++k) {
            float v = fmaf(acc[k], inv, d8[k]);
            o[k] = RELU ? fmaxf(v, 0.f) : v;
        }
        if constexpr (sizeof(OutT) == 2) {
            union { __half2 h[4]; float4 f; } u;
#pragma unroll
            for (int k = 0; k < 4; ++k)
                u.h[k] = __floats2half2_rn(o[2 * k], o[2 * k + 1]);
            *(float4*)&out[(size_t)node * 64 + doff] = u.f;
        } else {
            *(float4*)&out[(size_t)node * 64 + doff]     = make_float4(o[0], o[1], o[2], o[3]);
            *(float4*)&out[(size_t)node * 64 + doff + 4] = make_float4(o[4], o[5], o[6], o[7]);
        }
    }
}

extern "C" void kernel_launch(void* const* d_in, const int* in_sizes, int n_in,
                              void* d_out, int out_size, void* d_ws, size_t ws_size,
                              hipStream_t stream) {
    const float* x   = (const float*)d_in[0];
    const int*   ei  = (const int*)d_in[1];
    const float* w1l = (const float*)d_in[2];
    const float* b1l = (const float*)d_in[3];
    const float* w1r = (const float*)d_in[4];
    const float* w2l = (const float*)d_in[5];
    const float* b2l = (const float*)d_in[6];
    const float* w2r = (const float*)d_in[7];
    float* out = (float*)d_out;

    const int N = in_sizes[0] / DIM;   // 100000
    const int E = in_sizes[1] / 2;     // 1600000
    const int* src = ei;
    const int* dst = ei + E;
    const int nbuck = (N + BN - 1) / BN;           // 1563
    const int pb = (E + CHUNK - 1) / CHUNK;        // 391
    const int gb = (N + 255) / 256;                // 391

    // ws: ghist[nbuck] | boff[nbuck+1] | Hmat[pb*nbuck] | P[E] | spill[E] |
    //     (align 16) A fp16[N*64] | D fp16[N*64] | h1 fp16[N*64]
    int* ghist = (int*)d_ws;
    int* boff = ghist + nbuck;
    int* Hmat = boff + nbuck + 1;
    unsigned* P = (unsigned*)(Hmat + (size_t)pb * nbuck);
    int* spill = (int*)(P + E);
    uintptr_t ap = (uintptr_t)(spill + E);
    ap = (ap + 15) & ~(uintptr_t)15;
    __half* A  = (__half*)ap;
    __half* D  = A + (size_t)N * DIM;
    __half* h1 = D + (size_t)N * DIM;

    // ---- build ----
    hipMemsetAsync(ghist, 0, nbuck * sizeof(int), stream);
    hist_kernel<<<pb, 256, 0, stream>>>(dst, Hmat, ghist, E, nbuck);
    scan_kernel<<<1, 1024, 0, stream>>>(ghist, boff, nbuck);
    bases_kernel<<<(nbuck + 3) / 4, 256, 0, stream>>>(Hmat, boff, nbuck, pb);

    // ---- partition + layer-1 gemm (fused) ----
    part_gemm_kernel<<<pb + gb, 256, 0, stream>>>(src, dst, Hmat, P, E, nbuck, pb,
                                                  x, w1l, w1r, b1l, A, D, N);

    // ---- layer 1 gather ----
    gather_sort_combine<true, __half><<<nbuck, 256, 0, stream>>>(A, D, boff, P, spill, h1, N);

    // ---- layer 2 ----
    gemm_kernel<<<gb, 256, 0, stream>>>(h1, w2l, w2r, b2l, A, D, N);
    gather_sort_combine<false, float><<<nbuck, 256, 0, stream>>>(A, D, boff, P, spill, out, N);
}